// Round 8
// baseline (565.155 us; speedup 1.0000x reference)
//
#include <hip/hip_runtime.h>
#include <math.h>

// Problem constants (fixed shapes from reference)
#define B_ 2
#define N_ 16384
#define M_ 12000
#define F_ 16384

#define P_ 64           // face partitions (pmin granularity)
#define TILE_ 256       // faces per partition

typedef short bf16x8 __attribute__((ext_vector_type(8)));
typedef float f32x16 __attribute__((ext_vector_type(16)));

__device__ __host__ inline unsigned short bf16rn(float x) {
  unsigned int u = __float_as_uint(x);
  u = (u + 0x7FFFu + ((u >> 16) & 1u)) >> 16;
  return (unsigned short)u;
}
__device__ inline float bf16tof(unsigned short h) {
  return __uint_as_float(((unsigned int)h) << 16);
}

// ---------------------------------------------------------------------------
// Kernel A: per-face precompute.
//   fcurr[f] = (centroid_curr.xyz, |centroid_curr|^2)   (exact fp32 chain)
//   fnext[2f] = centroid_next, fnext[2f+1] = unit normal
//   fpack[f]  = 16 bf16 (32B): K=16 A-operand for mfma_32x32x16:
//     k0-3 {fhx,flx,fhx,flx} k4-7 {y} k8-11 {z} k12,13 {whi,wlo} k14,15 0
// ---------------------------------------------------------------------------
__global__ __launch_bounds__(256) void face_precomp(
    const float* __restrict__ obs_curr,
    const float* __restrict__ obs_next,
    const int* __restrict__ faces,
    float4* __restrict__ fcurr,
    float4* __restrict__ fnext,
    uint4* __restrict__ fpack) {
  int t = blockIdx.x * 256 + threadIdx.x;
  if (t >= B_ * F_) return;
  int b = t / F_;
  const float* oc = obs_curr + (size_t)b * M_ * 3;
  const float* on = obs_next + (size_t)b * M_ * 3;
  int i0 = faces[3 * (size_t)t + 0];
  int i1 = faces[3 * (size_t)t + 1];
  int i2 = faces[3 * (size_t)t + 2];

  float ax = oc[3*i0], ay = oc[3*i0+1], az = oc[3*i0+2];
  float bx = oc[3*i1], by = oc[3*i1+1], bz = oc[3*i1+2];
  float cx = oc[3*i2], cy = oc[3*i2+1], cz = oc[3*i2+2];
  float gx = (ax + bx + cx) / 3.0f;
  float gy = (ay + by + cy) / 3.0f;
  float gz = (az + bz + cz) / 3.0f;
  float w = gx*gx + gy*gy + gz*gz;
  fcurr[t] = make_float4(gx, gy, gz, w);

  float fx = -2.0f * gx, fy = -2.0f * gy, fz = -2.0f * gz;
  unsigned short fhx = bf16rn(fx), flx = bf16rn(fx - bf16tof(fhx));
  unsigned short fhy = bf16rn(fy), fly = bf16rn(fy - bf16tof(fhy));
  unsigned short fhz = bf16rn(fz), flz = bf16rn(fz - bf16tof(fhz));
  unsigned short whi = bf16rn(w),  wlo = bf16rn(w - bf16tof(whi));
  uint4 r0, r1;
  r0.x = (unsigned)fhx | ((unsigned)flx << 16);  // k0,k1
  r0.y = r0.x;                                    // k2,k3
  r0.z = (unsigned)fhy | ((unsigned)fly << 16);  // k4,k5
  r0.w = r0.z;                                    // k6,k7
  r1.x = (unsigned)fhz | ((unsigned)flz << 16);  // k8,k9
  r1.y = r1.x;                                    // k10,k11
  r1.z = (unsigned)whi | ((unsigned)wlo << 16);  // k12,k13
  r1.w = 0;                                       // k14,k15
  fpack[(size_t)t * 2 + 0] = r0;
  fpack[(size_t)t * 2 + 1] = r1;

  float nax = on[3*i0], nay = on[3*i0+1], naz = on[3*i0+2];
  float nbx = on[3*i1], nby = on[3*i1+1], nbz = on[3*i1+2];
  float ncx = on[3*i2], ncy = on[3*i2+1], ncz = on[3*i2+2];
  float hx = (nax + nbx + ncx) / 3.0f;
  float hy = (nay + nby + ncy) / 3.0f;
  float hz = (naz + nbz + ncz) / 3.0f;
  float e1x = nbx - nax, e1y = nby - nay, e1z = nbz - naz;
  float e2x = ncx - nax, e2y = ncy - nay, e2z = ncz - naz;
  float crx = e1y * e2z - e1z * e2y;
  float cry = e1z * e2x - e1x * e2z;
  float crz = e1x * e2y - e1y * e2x;
  float len = sqrtf(crx*crx + cry*cry + crz*crz);
  float inv = 1.0f / (len + 1e-12f);
  fnext[2 * (size_t)t + 0] = make_float4(hx, hy, hz, 0.0f);
  fnext[2 * (size_t)t + 1] = make_float4(crx*inv, cry*inv, crz*inv, 0.0f);
}

// ---------------------------------------------------------------------------
// Kernel B: 32x32x16 MFMA approximate-min pass, 4 B-frags per wave.
// Wave = 128 verts x 2048-face chunk: each A-load (32 faces) feeds 4 MFMAs
// (one per B-frag) -> L2 A-traffic 512->128 MB (round 7 was L2-BW-bound at
// ~15 us). Partition = 256 faces; fold 16 D-regs via min3 chains (~8
// VALU/MFMA). Grid 512 blocks (8 waves/CU); ILP across 4 fold chains +
// 16 MFMAs per load-group hides latency.
// ---------------------------------------------------------------------------
__global__ __launch_bounds__(256, 4) void knn_mfma32(
    const float* __restrict__ cloth_curr,
    const uint4* __restrict__ fpack,     // 2 x uint4 per face (32 B)
    float* __restrict__ pmin) {
  int bid = blockIdx.x;            // [0, 512)
  int s   = bid & 7;               // face chunk: [s*2048, (s+1)*2048)
  int vb  = (bid >> 3) & 31;       // 512-vert block
  int b   = bid >> 8;              // batch
  int lane = threadIdx.x & 63;
  int wid  = threadIdx.x >> 6;     // 0..3
  int h = lane >> 5;               // k-half
  int m = lane & 31;               // face-row / vert-col
  int vw = vb * 512 + wid * 128;   // wave's 128 verts

  // 4 B-frags: frag g = verts vw + g*32 + m (col=lane&31, k=8*h+j)
  const short one = (short)0x3F80;
  bf16x8 bfrag[4];
#pragma unroll
  for (int g = 0; g < 4; ++g) {
    const float* cp = cloth_curr + ((size_t)b * N_ + vw + g * 32 + m) * 3;
    float cxx = cp[0], cyy = cp[1], czz = cp[2];
    unsigned short chx = bf16rn(cxx), clx = bf16rn(cxx - bf16tof(chx));
    unsigned short chy = bf16rn(cyy), cly = bf16rn(cyy - bf16tof(chy));
    unsigned short chz = bf16rn(czz), clz = bf16rn(czz - bf16tof(chz));
    bf16x8 tq;
    if (h == 0) {
      tq[0] = (short)chx; tq[1] = (short)chx;
      tq[2] = (short)clx; tq[3] = (short)clx;
      tq[4] = (short)chy; tq[5] = (short)chy;
      tq[6] = (short)cly; tq[7] = (short)cly;
    } else {
      tq[0] = (short)chz; tq[1] = (short)chz;
      tq[2] = (short)clz; tq[3] = (short)clz;
      tq[4] = one; tq[5] = one;
      tq[6] = 0;   tq[7] = 0;
    }
    bfrag[g] = tq;
  }

  f32x16 zc;
#pragma unroll
  for (int k = 0; k < 16; ++k) zc[k] = 0.0f;

  // Per-lane A pointer: face (s*2048 + m), half h. Tile (32 faces) = 64
  // uint4; 4-tile group = 256 uint4; partition (256 faces) = 512 uint4.
  const uint4* fp = fpack + ((size_t)b * F_ + (size_t)s * 2048 + m) * 2 + h;
  float* pout = pmin + ((size_t)(b * P_ + s * 8)) * N_ + vw;

  for (int part = 0; part < 8; ++part) {   // 8 partitions of 256 faces
    float bmin[4];
#pragma unroll
    for (int g = 0; g < 4; ++g) bmin[g] = 3.4e38f;

#pragma unroll
    for (int half = 0; half < 2; ++half) { // 2 groups of 4 tiles
      uint4 a0 = fp[0];
      uint4 a1 = fp[64];
      uint4 a2 = fp[128];
      uint4 a3 = fp[192];
      fp += 256;
      uint4 araw[4] = {a0, a1, a2, a3};
#pragma unroll
      for (int t = 0; t < 4; ++t) {
        bf16x8 av = __builtin_bit_cast(bf16x8, araw[t]);
#pragma unroll
        for (int g = 0; g < 4; ++g) {
          f32x16 d = __builtin_amdgcn_mfma_f32_32x32x16_bf16(av, bfrag[g], zc, 0, 0, 0);
          // fold 16 -> 1 via min3-formable chains (8 ops)
          float v0 = fminf(fminf(d[0],  d[1]),  d[2]);
          float v1 = fminf(fminf(d[3],  d[4]),  d[5]);
          float v2 = fminf(fminf(d[6],  d[7]),  d[8]);
          float v3 = fminf(fminf(d[9],  d[10]), d[11]);
          float v4 = fminf(fminf(d[12], d[13]), d[14]);
          float w0 = fminf(fminf(v0, v1), v2);
          float w1 = fminf(fminf(v3, v4), d[15]);
          bmin[g] = fminf(fminf(w0, w1), bmin[g]);
        }
      }
    }
#pragma unroll
    for (int g = 0; g < 4; ++g) {
      float e = fminf(bmin[g], __shfl_xor(bmin[g], 32, 64));
      if (lane < 32) pout[g * 32 + lane] = e;
    }
    pout += N_;
  }
}

// ---------------------------------------------------------------------------
// Kernel C: per-(vertex,batch)-thread epilogue. Pick argmin partition from
// approx pmin (error ~1e-4 in d2-space; flips need a cross-partition
// near-tie — value impact << absmax threshold), then EXACT fp32 rescan of
// that 256-face partition (first-index on ties within the partition).
// ---------------------------------------------------------------------------
__global__ __launch_bounds__(256) void epilogue(
    const float* __restrict__ cloth_curr,
    const float* __restrict__ cloth_next,
    const float4* __restrict__ fcurr,
    const float4* __restrict__ fnext,
    const float* __restrict__ pmin,
    const int* __restrict__ iter_num,
    float* __restrict__ out,
    float* __restrict__ block_sums) {
  int t = blockIdx.x * 256 + threadIdx.x;  // [0, 2*N)
  int i = t >> 1;                          // vertex
  int b = t & 1;                           // batch

  // weight ramp (double to match Python scalar math)
  int it = *iter_num;
  double itc = (double)(it - 50000);
  if (itc < 0.0) itc = 0.0;
  double prog = itc / 100000.0;
  if (prog > 1.0) prog = 1.0;
  float weight = (float)(1e-3 + (5e3 - 1e-3) * prog);
  float scale = weight * 0.5f;  // weight / B

  // pass 1: argmin partition over approx partition minima (coalesced)
  float best = 3.4e38f;
  int bp = 0;
#pragma unroll 8
  for (int p = 0; p < P_; ++p) {
    float s = pmin[((size_t)(b * P_ + p)) * N_ + i];
    bool mm = s < best;
    best = mm ? s : best;
    bp = mm ? p : bp;
  }

  // pass 2: exact fp32 rescan of winning partition
  const float* cp = cloth_curr + ((size_t)b * N_ + i) * 3;
  float m2x = -2.0f * cp[0];
  float m2y = -2.0f * cp[1];
  float m2z = -2.0f * cp[2];
  const float4* fpp = fcurr + (size_t)b * F_ + (size_t)bp * TILE_;
  float sbest = 3.4e38f;
  int jwin = 0;
#pragma unroll 4
  for (int j = 0; j < TILE_; ++j) {
    float4 fc = fpp[j];
    float s = fmaf(m2x, fc.x, fmaf(m2y, fc.y, fmaf(m2z, fc.z, fc.w)));
    bool u = s < sbest;
    sbest = u ? s : sbest;
    jwin = u ? j : jwin;
  }
  int fidx = bp * TILE_ + jwin;

  float4 cent = fnext[2 * ((size_t)b * F_ + fidx) + 0];
  float4 nrm  = fnext[2 * ((size_t)b * F_ + fidx) + 1];
  const float* np2 = cloth_next + ((size_t)b * N_ + i) * 3;
  float dist = (np2[0] - cent.x) * nrm.x +
               (np2[1] - cent.y) * nrm.y +
               (np2[2] - cent.z) * nrm.z;
  float ip = fmaxf(1e-3f - dist, 0.0f);
  float acc = ip * ip * ip * scale;

  // combine the two batches (lanes 2k / 2k+1 hold b=0 / b=1 of vertex i)
  float pair = acc + __shfl_xor(acc, 1, 64);
  if (b == 0) out[1 + i] = pair;  // per_vert

  // block-level loss partial (deterministic: no atomics)
  float r = acc;
#pragma unroll
  for (int off = 32; off > 0; off >>= 1) r += __shfl_down(r, off, 64);
  __shared__ float wsum[4];
  int lane = threadIdx.x & 63;
  int w = threadIdx.x >> 6;
  if (lane == 0) wsum[w] = r;
  __syncthreads();
  if (threadIdx.x == 0)
    block_sums[blockIdx.x] = wsum[0] + wsum[1] + wsum[2] + wsum[3];
}

__global__ void final_sum(const float* __restrict__ block_sums,
                          float* __restrict__ out) {
  // 128 partials, 64 threads
  float v = block_sums[threadIdx.x] + block_sums[threadIdx.x + 64];
#pragma unroll
  for (int off = 32; off > 0; off >>= 1) v += __shfl_down(v, off, 64);
  if (threadIdx.x == 0) out[0] = v;
}

// ---------------------------------------------------------------------------
extern "C" void kernel_launch(void* const* d_in, const int* in_sizes, int n_in,
                              void* d_out, int out_size, void* d_ws, size_t ws_size,
                              hipStream_t stream) {
  const float* cloth_curr = (const float*)d_in[0];
  const float* cloth_next = (const float*)d_in[1];
  const float* obs_curr   = (const float*)d_in[2];
  const float* obs_next   = (const float*)d_in[3];
  const int*   faces      = (const int*)d_in[4];
  const int*   iter_num   = (const int*)d_in[5];
  float* out = (float*)d_out;

  // workspace: fcurr 512K @0 | fnext 1M @512K | fpack 1M @1.5M |
  //            pmin 8M @3.5M | block_sums after pmin
  char* w = (char*)d_ws;
  float4* fcurr = (float4*)(w);
  float4* fnext = (float4*)(w + 524288);
  uint4*  fpack = (uint4*)(w + 1572864);
  float*  pmin  = (float*)(w + 3670016);
  float* block_sums = (float*)(w + 3670016 + (size_t)B_ * P_ * N_ * 4);

  face_precomp<<<(B_ * F_ + 255) / 256, 256, 0, stream>>>(
      obs_curr, obs_next, faces, fcurr, fnext, fpack);

  knn_mfma32<<<512, 256, 0, stream>>>(cloth_curr, fpack, pmin);

  epilogue<<<(2 * N_) / 256, 256, 0, stream>>>(
      cloth_curr, cloth_next, fcurr, fnext, pmin, iter_num, out, block_sums);

  final_sum<<<1, 64, 0, stream>>>(block_sums, out);
}

// Round 9
// 123.245 us; speedup vs baseline: 4.5856x; 4.5856x over previous
//
#include <hip/hip_runtime.h>
#include <math.h>

// Problem constants (fixed shapes from reference)
#define B_ 2
#define N_ 16384
#define M_ 12000
#define F_ 16384

#define P_ 128          // face partitions (pmin granularity)
#define TILE_ 128       // faces per partition

typedef short bf16x8 __attribute__((ext_vector_type(8)));
typedef float f32x16 __attribute__((ext_vector_type(16)));

__device__ __host__ inline unsigned short bf16rn(float x) {
  unsigned int u = __float_as_uint(x);
  u = (u + 0x7FFFu + ((u >> 16) & 1u)) >> 16;
  return (unsigned short)u;
}
__device__ inline float bf16tof(unsigned short h) {
  return __uint_as_float(((unsigned int)h) << 16);
}

// ---------------------------------------------------------------------------
// Kernel A: per-face precompute + out[0] zero-init (replaces final_sum's
// job; epilogue atomically accumulates into out[0]).
//   fcurr[f] = (centroid_curr.xyz, |centroid_curr|^2)   (exact fp32 chain)
//   fnext[2f] = centroid_next, fnext[2f+1] = unit normal
//   fpack[f]  = 16 bf16 (32B): K=16 A-operand for mfma_32x32x16:
//     k0-3 {fhx,flx,fhx,flx} k4-7 {y} k8-11 {z} k12,13 {whi,wlo} k14,15 0
// ---------------------------------------------------------------------------
__global__ __launch_bounds__(256) void face_precomp(
    const float* __restrict__ obs_curr,
    const float* __restrict__ obs_next,
    const int* __restrict__ faces,
    float4* __restrict__ fcurr,
    float4* __restrict__ fnext,
    uint4* __restrict__ fpack,
    float* __restrict__ out) {
  int t = blockIdx.x * 256 + threadIdx.x;
  if (t == 0) out[0] = 0.0f;  // epilogue (next kernel, same stream) accumulates
  if (t >= B_ * F_) return;
  int b = t / F_;
  const float* oc = obs_curr + (size_t)b * M_ * 3;
  const float* on = obs_next + (size_t)b * M_ * 3;
  int i0 = faces[3 * (size_t)t + 0];
  int i1 = faces[3 * (size_t)t + 1];
  int i2 = faces[3 * (size_t)t + 2];

  float ax = oc[3*i0], ay = oc[3*i0+1], az = oc[3*i0+2];
  float bx = oc[3*i1], by = oc[3*i1+1], bz = oc[3*i1+2];
  float cx = oc[3*i2], cy = oc[3*i2+1], cz = oc[3*i2+2];
  float gx = (ax + bx + cx) / 3.0f;
  float gy = (ay + by + cy) / 3.0f;
  float gz = (az + bz + cz) / 3.0f;
  float w = gx*gx + gy*gy + gz*gz;
  fcurr[t] = make_float4(gx, gy, gz, w);

  float fx = -2.0f * gx, fy = -2.0f * gy, fz = -2.0f * gz;
  unsigned short fhx = bf16rn(fx), flx = bf16rn(fx - bf16tof(fhx));
  unsigned short fhy = bf16rn(fy), fly = bf16rn(fy - bf16tof(fhy));
  unsigned short fhz = bf16rn(fz), flz = bf16rn(fz - bf16tof(fhz));
  unsigned short whi = bf16rn(w),  wlo = bf16rn(w - bf16tof(whi));
  uint4 r0, r1;
  r0.x = (unsigned)fhx | ((unsigned)flx << 16);  // k0,k1
  r0.y = r0.x;                                    // k2,k3
  r0.z = (unsigned)fhy | ((unsigned)fly << 16);  // k4,k5
  r0.w = r0.z;                                    // k6,k7
  r1.x = (unsigned)fhz | ((unsigned)flz << 16);  // k8,k9
  r1.y = r1.x;                                    // k10,k11
  r1.z = (unsigned)whi | ((unsigned)wlo << 16);  // k12,k13
  r1.w = 0;                                       // k14,k15
  fpack[(size_t)t * 2 + 0] = r0;
  fpack[(size_t)t * 2 + 1] = r1;

  float nax = on[3*i0], nay = on[3*i0+1], naz = on[3*i0+2];
  float nbx = on[3*i1], nby = on[3*i1+1], nbz = on[3*i1+2];
  float ncx = on[3*i2], ncy = on[3*i2+1], ncz = on[3*i2+2];
  float hx = (nax + nbx + ncx) / 3.0f;
  float hy = (nay + nby + ncy) / 3.0f;
  float hz = (naz + nbz + ncz) / 3.0f;
  float e1x = nbx - nax, e1y = nby - nay, e1z = nbz - naz;
  float e2x = ncx - nax, e2y = ncy - nay, e2z = ncz - naz;
  float crx = e1y * e2z - e1z * e2y;
  float cry = e1z * e2x - e1x * e2z;
  float crz = e1x * e2y - e1y * e2x;
  float len = sqrtf(crx*crx + cry*cry + crz*crz);
  float inv = 1.0f / (len + 1e-12f);
  fnext[2 * (size_t)t + 0] = make_float4(hx, hy, hz, 0.0f);
  fnext[2 * (size_t)t + 1] = make_float4(crx*inv, cry*inv, crz*inv, 0.0f);
}

// ---------------------------------------------------------------------------
// Kernel B: 32x32x16 MFMA approximate-min pass (round-7 structure, proven
// no-spill at ~16 us — at ~85% of the 13.7 us per-CU VALU fold floor).
// Wave = 32 verts (one B-frag) x 2048-face chunk; per partition (128 faces):
// 4 imm-offset dwordx4 loads + 4 MFMA + min3-chain fold + shfl + store.
// DO NOT add more B-frags / unroll: round 8 showed 16 in-flight D-tuples
// spill to scratch (1.9 GB/dispatch HBM traffic, 443 us).
// ---------------------------------------------------------------------------
__global__ __launch_bounds__(256, 4) void knn_mfma32(
    const float* __restrict__ cloth_curr,
    const uint4* __restrict__ fpack,     // 2 x uint4 per face (32 B)
    float* __restrict__ pmin) {
  int bid = blockIdx.x;            // [0, 2048)
  int s   = bid & 7;               // face chunk: [s*2048, (s+1)*2048)
  int vgb = (bid >> 3) & 127;      // vertex group of 128
  int b   = bid >> 10;             // batch
  int lane = threadIdx.x & 63;
  int wid  = threadIdx.x >> 6;     // 0..3
  int h = lane >> 5;               // k-half
  int m = lane & 31;               // face-row / vert-col
  int vw = vgb * 128 + wid * 32;   // wave's 32 verts

  // B-frag for vert vw+m (col = lane&31, k = 8*h + j)
  const float* cp = cloth_curr + ((size_t)b * N_ + vw + m) * 3;
  float cxx = cp[0], cyy = cp[1], czz = cp[2];
  unsigned short chx = bf16rn(cxx), clx = bf16rn(cxx - bf16tof(chx));
  unsigned short chy = bf16rn(cyy), cly = bf16rn(cyy - bf16tof(chy));
  unsigned short chz = bf16rn(czz), clz = bf16rn(czz - bf16tof(chz));
  const short one = (short)0x3F80;
  bf16x8 bfrag;
  if (h == 0) {
    bfrag[0] = (short)chx; bfrag[1] = (short)chx;
    bfrag[2] = (short)clx; bfrag[3] = (short)clx;
    bfrag[4] = (short)chy; bfrag[5] = (short)chy;
    bfrag[6] = (short)cly; bfrag[7] = (short)cly;
  } else {
    bfrag[0] = (short)chz; bfrag[1] = (short)chz;
    bfrag[2] = (short)clz; bfrag[3] = (short)clz;
    bfrag[4] = one; bfrag[5] = one;
    bfrag[6] = 0;   bfrag[7] = 0;
  }

  f32x16 zc;
#pragma unroll
  for (int k = 0; k < 16; ++k) zc[k] = 0.0f;

  // Per-lane A pointer: face (s*2048 + m), half h; tiles at +64/128/192,
  // partitions advance by 256 uint4 (128 faces * 32 B).
  const uint4* fp = fpack + ((size_t)b * F_ + (size_t)s * 2048 + m) * 2 + h;
  float* pout = pmin + ((size_t)(b * P_ + s * 16)) * N_ + vw + m;

  for (int part = 0; part < 16; ++part) {
    uint4 a0 = fp[0];
    uint4 a1 = fp[64];
    uint4 a2 = fp[128];
    uint4 a3 = fp[192];
    fp += 256;
    f32x16 d0 = __builtin_amdgcn_mfma_f32_32x32x16_bf16(
        __builtin_bit_cast(bf16x8, a0), bfrag, zc, 0, 0, 0);
    f32x16 d1 = __builtin_amdgcn_mfma_f32_32x32x16_bf16(
        __builtin_bit_cast(bf16x8, a1), bfrag, zc, 0, 0, 0);
    f32x16 d2 = __builtin_amdgcn_mfma_f32_32x32x16_bf16(
        __builtin_bit_cast(bf16x8, a2), bfrag, zc, 0, 0, 0);
    f32x16 d3 = __builtin_amdgcn_mfma_f32_32x32x16_bf16(
        __builtin_bit_cast(bf16x8, a3), bfrag, zc, 0, 0, 0);

    // min over 64 regs; min(min(a,b),c) chains fuse to v_min3_f32
    float r[8];
#pragma unroll
    for (int k = 0; k < 8; ++k) {
      float v = fminf(fminf(d0[k], d0[k + 8]), d1[k]);
      v = fminf(fminf(v, d1[k + 8]), d2[k]);
      v = fminf(fminf(v, d2[k + 8]), d3[k]);
      v = fminf(v, d3[k + 8]);
      r[k] = v;
    }
    float t1 = fminf(fminf(r[0], r[1]), r[2]);
    t1 = fminf(fminf(t1, r[3]), r[4]);
    t1 = fminf(fminf(t1, r[5]), r[6]);
    float bmin = fminf(t1, r[7]);
    bmin = fminf(bmin, __shfl_xor(bmin, 32, 64));
    if (lane < 32) *pout = bmin;
    pout += N_;
  }
}

// ---------------------------------------------------------------------------
// Kernel C: per-(vertex,batch)-thread epilogue. Pick argmin partition from
// approx pmin (split-bf16 error ~1e-4 in d2-space; flips need a
// cross-partition near-tie — value impact << absmax threshold), then EXACT
// fp32 rescan of that 128-face partition (first-index tie within it).
// Loss accumulated via one atomicAdd per block (out[0] zeroed by
// face_precomp earlier in the stream) — removes the final_sum launch.
// ---------------------------------------------------------------------------
__global__ __launch_bounds__(256) void epilogue(
    const float* __restrict__ cloth_curr,
    const float* __restrict__ cloth_next,
    const float4* __restrict__ fcurr,
    const float4* __restrict__ fnext,
    const float* __restrict__ pmin,
    const int* __restrict__ iter_num,
    float* __restrict__ out) {
  int t = blockIdx.x * 256 + threadIdx.x;  // [0, 2*N)
  int i = t >> 1;                          // vertex
  int b = t & 1;                           // batch

  // weight ramp (double to match Python scalar math)
  int it = *iter_num;
  double itc = (double)(it - 50000);
  if (itc < 0.0) itc = 0.0;
  double prog = itc / 100000.0;
  if (prog > 1.0) prog = 1.0;
  float weight = (float)(1e-3 + (5e3 - 1e-3) * prog);
  float scale = weight * 0.5f;  // weight / B

  // pass 1: argmin partition over approx partition minima (coalesced)
  float best = 3.4e38f;
  int bp = 0;
#pragma unroll 8
  for (int p = 0; p < P_; ++p) {
    float s = pmin[((size_t)(b * P_ + p)) * N_ + i];
    bool mm = s < best;
    best = mm ? s : best;
    bp = mm ? p : bp;
  }

  // pass 2: exact fp32 rescan of winning partition
  const float* cp = cloth_curr + ((size_t)b * N_ + i) * 3;
  float m2x = -2.0f * cp[0];
  float m2y = -2.0f * cp[1];
  float m2z = -2.0f * cp[2];
  const float4* fpp = fcurr + (size_t)b * F_ + (size_t)bp * TILE_;
  float sbest = 3.4e38f;
  int jwin = 0;
#pragma unroll 4
  for (int j = 0; j < TILE_; ++j) {
    float4 fc = fpp[j];
    float s = fmaf(m2x, fc.x, fmaf(m2y, fc.y, fmaf(m2z, fc.z, fc.w)));
    bool u = s < sbest;
    sbest = u ? s : sbest;
    jwin = u ? j : jwin;
  }
  int fidx = bp * TILE_ + jwin;

  float4 cent = fnext[2 * ((size_t)b * F_ + fidx) + 0];
  float4 nrm  = fnext[2 * ((size_t)b * F_ + fidx) + 1];
  const float* np2 = cloth_next + ((size_t)b * N_ + i) * 3;
  float dist = (np2[0] - cent.x) * nrm.x +
               (np2[1] - cent.y) * nrm.y +
               (np2[2] - cent.z) * nrm.z;
  float ip = fmaxf(1e-3f - dist, 0.0f);
  float acc = ip * ip * ip * scale;

  // combine the two batches (lanes 2k / 2k+1 hold b=0 / b=1 of vertex i)
  float pair = acc + __shfl_xor(acc, 1, 64);
  if (b == 0) out[1 + i] = pair;  // per_vert

  // block-level loss partial -> one atomic per block
  float r = acc;
#pragma unroll
  for (int off = 32; off > 0; off >>= 1) r += __shfl_down(r, off, 64);
  __shared__ float wsum[4];
  int lane = threadIdx.x & 63;
  int w = threadIdx.x >> 6;
  if (lane == 0) wsum[w] = r;
  __syncthreads();
  if (threadIdx.x == 0)
    atomicAdd(out, (wsum[0] + wsum[1]) + (wsum[2] + wsum[3]));
}

// ---------------------------------------------------------------------------
extern "C" void kernel_launch(void* const* d_in, const int* in_sizes, int n_in,
                              void* d_out, int out_size, void* d_ws, size_t ws_size,
                              hipStream_t stream) {
  const float* cloth_curr = (const float*)d_in[0];
  const float* cloth_next = (const float*)d_in[1];
  const float* obs_curr   = (const float*)d_in[2];
  const float* obs_next   = (const float*)d_in[3];
  const int*   faces      = (const int*)d_in[4];
  const int*   iter_num   = (const int*)d_in[5];
  float* out = (float*)d_out;

  // workspace: fcurr 512K @0 | fnext 1M @512K | fpack 1M @1.5M | pmin 16M @3.5M
  char* w = (char*)d_ws;
  float4* fcurr = (float4*)(w);
  float4* fnext = (float4*)(w + 524288);
  uint4*  fpack = (uint4*)(w + 1572864);
  float*  pmin  = (float*)(w + 3670016);

  face_precomp<<<(B_ * F_ + 255) / 256, 256, 0, stream>>>(
      obs_curr, obs_next, faces, fcurr, fnext, fpack, out);

  knn_mfma32<<<2048, 256, 0, stream>>>(cloth_curr, fpack, pmin);

  epilogue<<<(2 * N_) / 256, 256, 0, stream>>>(
      cloth_curr, cloth_next, fcurr, fnext, pmin, iter_num, out);
}

// Round 10
// 118.533 us; speedup vs baseline: 4.7679x; 1.0397x over previous
//
#include <hip/hip_runtime.h>
#include <math.h>

// Problem constants (fixed shapes from reference)
#define B_ 2
#define N_ 16384
#define M_ 12000
#define F_ 16384

#define P_ 128          // face partitions (pmin granularity)
#define TILE_ 128       // faces per partition

typedef short bf16x8 __attribute__((ext_vector_type(8)));
typedef float f32x16 __attribute__((ext_vector_type(16)));

__device__ __host__ inline unsigned short bf16rn(float x) {
  unsigned int u = __float_as_uint(x);
  u = (u + 0x7FFFu + ((u >> 16) & 1u)) >> 16;
  return (unsigned short)u;
}
__device__ inline float bf16tof(unsigned short h) {
  return __uint_as_float(((unsigned int)h) << 16);
}

// ---------------------------------------------------------------------------
// Kernel A: per-face precompute + out[0] zero-init.
//   fcurr[f] = (centroid_curr.xyz, |centroid_curr|^2)   (exact fp32 chain)
//   fnext[2f] = centroid_next, fnext[2f+1] = unit normal
//   fpack[f]  = 16 bf16 (32B): K=16 A-operand for mfma_32x32x16:
//     k0-3 {fhx,flx,fhx,flx} k4-7 {y} k8-11 {z} k12,13 {whi,wlo} k14,15 0
// ---------------------------------------------------------------------------
__global__ __launch_bounds__(256) void face_precomp(
    const float* __restrict__ obs_curr,
    const float* __restrict__ obs_next,
    const int* __restrict__ faces,
    float4* __restrict__ fcurr,
    float4* __restrict__ fnext,
    uint4* __restrict__ fpack,
    float* __restrict__ out) {
  int t = blockIdx.x * 256 + threadIdx.x;
  if (t == 0) out[0] = 0.0f;  // epilogue (later, same stream) accumulates
  if (t >= B_ * F_) return;
  int b = t / F_;
  const float* oc = obs_curr + (size_t)b * M_ * 3;
  const float* on = obs_next + (size_t)b * M_ * 3;
  int i0 = faces[3 * (size_t)t + 0];
  int i1 = faces[3 * (size_t)t + 1];
  int i2 = faces[3 * (size_t)t + 2];

  float ax = oc[3*i0], ay = oc[3*i0+1], az = oc[3*i0+2];
  float bx = oc[3*i1], by = oc[3*i1+1], bz = oc[3*i1+2];
  float cx = oc[3*i2], cy = oc[3*i2+1], cz = oc[3*i2+2];
  float gx = (ax + bx + cx) / 3.0f;
  float gy = (ay + by + cy) / 3.0f;
  float gz = (az + bz + cz) / 3.0f;
  float w = gx*gx + gy*gy + gz*gz;
  fcurr[t] = make_float4(gx, gy, gz, w);

  float fx = -2.0f * gx, fy = -2.0f * gy, fz = -2.0f * gz;
  unsigned short fhx = bf16rn(fx), flx = bf16rn(fx - bf16tof(fhx));
  unsigned short fhy = bf16rn(fy), fly = bf16rn(fy - bf16tof(fhy));
  unsigned short fhz = bf16rn(fz), flz = bf16rn(fz - bf16tof(fhz));
  unsigned short whi = bf16rn(w),  wlo = bf16rn(w - bf16tof(whi));
  uint4 r0, r1;
  r0.x = (unsigned)fhx | ((unsigned)flx << 16);  // k0,k1
  r0.y = r0.x;                                    // k2,k3
  r0.z = (unsigned)fhy | ((unsigned)fly << 16);  // k4,k5
  r0.w = r0.z;                                    // k6,k7
  r1.x = (unsigned)fhz | ((unsigned)flz << 16);  // k8,k9
  r1.y = r1.x;                                    // k10,k11
  r1.z = (unsigned)whi | ((unsigned)wlo << 16);  // k12,k13
  r1.w = 0;                                       // k14,k15
  fpack[(size_t)t * 2 + 0] = r0;
  fpack[(size_t)t * 2 + 1] = r1;

  float nax = on[3*i0], nay = on[3*i0+1], naz = on[3*i0+2];
  float nbx = on[3*i1], nby = on[3*i1+1], nbz = on[3*i1+2];
  float ncx = on[3*i2], ncy = on[3*i2+1], ncz = on[3*i2+2];
  float hx = (nax + nbx + ncx) / 3.0f;
  float hy = (nay + nby + ncy) / 3.0f;
  float hz = (naz + nbz + ncz) / 3.0f;
  float e1x = nbx - nax, e1y = nby - nay, e1z = nbz - naz;
  float e2x = ncx - nax, e2y = ncy - nay, e2z = ncz - naz;
  float crx = e1y * e2z - e1z * e2y;
  float cry = e1z * e2x - e1x * e2z;
  float crz = e1x * e2y - e1y * e2x;
  float len = sqrtf(crx*crx + cry*cry + crz*crz);
  float inv = 1.0f / (len + 1e-12f);
  fnext[2 * (size_t)t + 0] = make_float4(hx, hy, hz, 0.0f);
  fnext[2 * (size_t)t + 1] = make_float4(crx*inv, cry*inv, crz*inv, 0.0f);
}

// ---------------------------------------------------------------------------
// Kernel B: 32x32x16 MFMA approximate-min pass, 2 B-frags per wave.
// Round 9 analysis: knn is L2-BW-bound (8192 waves x 64 KB chunk = 512 MB
// L2 reads ~= 15 us). 2 B-frags (64 verts/wave) halve that to 256 MB with
// only <=4 live D-tuples (64 VGPRs; round 8's 4-frag full unroll held 16 ->
// scratch spill catastrophe). Fold: per-k running min3 accumulators,
// 8 v_min3 per MFMA. Grid 1024 blocks = 4 blocks/CU, 16 waves/CU.
// ---------------------------------------------------------------------------
__global__ __launch_bounds__(256, 4) void knn_mfma32(
    const float* __restrict__ cloth_curr,
    const uint4* __restrict__ fpack,     // 2 x uint4 per face (32 B)
    float* __restrict__ pmin) {
  int bid = blockIdx.x;            // [0, 1024)
  int s   = bid & 7;               // face chunk: [s*2048, (s+1)*2048)
  int vb  = (bid >> 3) & 63;       // 256-vert block
  int b   = bid >> 9;              // batch
  int lane = threadIdx.x & 63;
  int wid  = threadIdx.x >> 6;     // 0..3
  int h = lane >> 5;               // k-half
  int m = lane & 31;               // face-row / vert-col
  int vw = vb * 256 + wid * 64;    // wave's 64 verts

  // 2 B-frags: frag g covers verts vw + g*32 + m (col=lane&31, k=8*h+j)
  const short one = (short)0x3F80;
  bf16x8 bfrag0, bfrag1;
#pragma unroll
  for (int g = 0; g < 2; ++g) {
    const float* cp = cloth_curr + ((size_t)b * N_ + vw + g * 32 + m) * 3;
    float cxx = cp[0], cyy = cp[1], czz = cp[2];
    unsigned short chx = bf16rn(cxx), clx = bf16rn(cxx - bf16tof(chx));
    unsigned short chy = bf16rn(cyy), cly = bf16rn(cyy - bf16tof(chy));
    unsigned short chz = bf16rn(czz), clz = bf16rn(czz - bf16tof(chz));
    bf16x8 tq;
    if (h == 0) {
      tq[0] = (short)chx; tq[1] = (short)chx;
      tq[2] = (short)clx; tq[3] = (short)clx;
      tq[4] = (short)chy; tq[5] = (short)chy;
      tq[6] = (short)cly; tq[7] = (short)cly;
    } else {
      tq[0] = (short)chz; tq[1] = (short)chz;
      tq[2] = (short)clz; tq[3] = (short)clz;
      tq[4] = one; tq[5] = one;
      tq[6] = 0;   tq[7] = 0;
    }
    if (g == 0) bfrag0 = tq; else bfrag1 = tq;
  }

  f32x16 zc;
#pragma unroll
  for (int k = 0; k < 16; ++k) zc[k] = 0.0f;

  // Per-lane A pointer: face (s*2048 + m), half h. Tile (32 faces) = 64
  // uint4; 2-tile group = 128 uint4; partition (128 faces) = 256 uint4.
  const uint4* fp = fpack + ((size_t)b * F_ + (size_t)s * 2048 + m) * 2 + h;
  float* pout = pmin + ((size_t)(b * P_ + s * 16)) * N_ + vw;

  for (int part = 0; part < 16; ++part) {
    float r0[8], r1[8];
#pragma unroll
    for (int k = 0; k < 8; ++k) { r0[k] = 3.4e38f; r1[k] = 3.4e38f; }

#pragma unroll
    for (int grp = 0; grp < 2; ++grp) {   // 2 groups of 2 tiles
      uint4 a0 = fp[0];
      uint4 a1 = fp[64];
      fp += 128;
      bf16x8 av0 = __builtin_bit_cast(bf16x8, a0);
      bf16x8 av1 = __builtin_bit_cast(bf16x8, a1);
      f32x16 d00 = __builtin_amdgcn_mfma_f32_32x32x16_bf16(av0, bfrag0, zc, 0, 0, 0);
      f32x16 d01 = __builtin_amdgcn_mfma_f32_32x32x16_bf16(av0, bfrag1, zc, 0, 0, 0);
      f32x16 d10 = __builtin_amdgcn_mfma_f32_32x32x16_bf16(av1, bfrag0, zc, 0, 0, 0);
      f32x16 d11 = __builtin_amdgcn_mfma_f32_32x32x16_bf16(av1, bfrag1, zc, 0, 0, 0);
      // per-k running accumulators; min(min(a,b),c) fuses to v_min3_f32
#pragma unroll
      for (int k = 0; k < 8; ++k) {
        r0[k] = fminf(fminf(d00[k], d00[k + 8]), r0[k]);
        r0[k] = fminf(fminf(d10[k], d10[k + 8]), r0[k]);
        r1[k] = fminf(fminf(d01[k], d01[k + 8]), r1[k]);
        r1[k] = fminf(fminf(d11[k], d11[k + 8]), r1[k]);
      }
    }
    // fold 8 -> 1 per frag, merge halves, store
    float t0 = fminf(fminf(r0[0], r0[1]), r0[2]);
    t0 = fminf(fminf(t0, r0[3]), r0[4]);
    t0 = fminf(fminf(t0, r0[5]), r0[6]);
    float bmin0 = fminf(t0, r0[7]);
    float t1 = fminf(fminf(r1[0], r1[1]), r1[2]);
    t1 = fminf(fminf(t1, r1[3]), r1[4]);
    t1 = fminf(fminf(t1, r1[5]), r1[6]);
    float bmin1 = fminf(t1, r1[7]);
    bmin0 = fminf(bmin0, __shfl_xor(bmin0, 32, 64));
    bmin1 = fminf(bmin1, __shfl_xor(bmin1, 32, 64));
    if (lane < 32) {
      pout[lane] = bmin0;
      pout[32 + lane] = bmin1;
    }
    pout += N_;
  }
}

// ---------------------------------------------------------------------------
// Kernel C: per-(vertex,batch)-thread epilogue (round-9, verified).
// Pick argmin partition from approx pmin, EXACT fp32 rescan of that
// 128-face partition, plane distance + interpenetration; one atomic per
// block into out[0].
// ---------------------------------------------------------------------------
__global__ __launch_bounds__(256) void epilogue(
    const float* __restrict__ cloth_curr,
    const float* __restrict__ cloth_next,
    const float4* __restrict__ fcurr,
    const float4* __restrict__ fnext,
    const float* __restrict__ pmin,
    const int* __restrict__ iter_num,
    float* __restrict__ out) {
  int t = blockIdx.x * 256 + threadIdx.x;  // [0, 2*N)
  int i = t >> 1;                          // vertex
  int b = t & 1;                           // batch

  // weight ramp (double to match Python scalar math)
  int it = *iter_num;
  double itc = (double)(it - 50000);
  if (itc < 0.0) itc = 0.0;
  double prog = itc / 100000.0;
  if (prog > 1.0) prog = 1.0;
  float weight = (float)(1e-3 + (5e3 - 1e-3) * prog);
  float scale = weight * 0.5f;  // weight / B

  // pass 1: argmin partition over approx partition minima (coalesced)
  float best = 3.4e38f;
  int bp = 0;
#pragma unroll 8
  for (int p = 0; p < P_; ++p) {
    float s = pmin[((size_t)(b * P_ + p)) * N_ + i];
    bool mm = s < best;
    best = mm ? s : best;
    bp = mm ? p : bp;
  }

  // pass 2: exact fp32 rescan of winning partition
  const float* cp = cloth_curr + ((size_t)b * N_ + i) * 3;
  float m2x = -2.0f * cp[0];
  float m2y = -2.0f * cp[1];
  float m2z = -2.0f * cp[2];
  const float4* fpp = fcurr + (size_t)b * F_ + (size_t)bp * TILE_;
  float sbest = 3.4e38f;
  int jwin = 0;
#pragma unroll 4
  for (int j = 0; j < TILE_; ++j) {
    float4 fc = fpp[j];
    float s = fmaf(m2x, fc.x, fmaf(m2y, fc.y, fmaf(m2z, fc.z, fc.w)));
    bool u = s < sbest;
    sbest = u ? s : sbest;
    jwin = u ? j : jwin;
  }
  int fidx = bp * TILE_ + jwin;

  float4 cent = fnext[2 * ((size_t)b * F_ + fidx) + 0];
  float4 nrm  = fnext[2 * ((size_t)b * F_ + fidx) + 1];
  const float* np2 = cloth_next + ((size_t)b * N_ + i) * 3;
  float dist = (np2[0] - cent.x) * nrm.x +
               (np2[1] - cent.y) * nrm.y +
               (np2[2] - cent.z) * nrm.z;
  float ip = fmaxf(1e-3f - dist, 0.0f);
  float acc = ip * ip * ip * scale;

  // combine the two batches (lanes 2k / 2k+1 hold b=0 / b=1 of vertex i)
  float pair = acc + __shfl_xor(acc, 1, 64);
  if (b == 0) out[1 + i] = pair;  // per_vert

  // block-level loss partial -> one atomic per block
  float r = acc;
#pragma unroll
  for (int off = 32; off > 0; off >>= 1) r += __shfl_down(r, off, 64);
  __shared__ float wsum[4];
  int lane = threadIdx.x & 63;
  int w = threadIdx.x >> 6;
  if (lane == 0) wsum[w] = r;
  __syncthreads();
  if (threadIdx.x == 0)
    atomicAdd(out, (wsum[0] + wsum[1]) + (wsum[2] + wsum[3]));
}

// ---------------------------------------------------------------------------
extern "C" void kernel_launch(void* const* d_in, const int* in_sizes, int n_in,
                              void* d_out, int out_size, void* d_ws, size_t ws_size,
                              hipStream_t stream) {
  const float* cloth_curr = (const float*)d_in[0];
  const float* cloth_next = (const float*)d_in[1];
  const float* obs_curr   = (const float*)d_in[2];
  const float* obs_next   = (const float*)d_in[3];
  const int*   faces      = (const int*)d_in[4];
  const int*   iter_num   = (const int*)d_in[5];
  float* out = (float*)d_out;

  // workspace: fcurr 512K @0 | fnext 1M @512K | fpack 1M @1.5M | pmin 16M @3.5M
  char* w = (char*)d_ws;
  float4* fcurr = (float4*)(w);
  float4* fnext = (float4*)(w + 524288);
  uint4*  fpack = (uint4*)(w + 1572864);
  float*  pmin  = (float*)(w + 3670016);

  face_precomp<<<(B_ * F_ + 255) / 256, 256, 0, stream>>>(
      obs_curr, obs_next, faces, fcurr, fnext, fpack, out);

  knn_mfma32<<<1024, 256, 0, stream>>>(cloth_curr, fpack, pmin);

  epilogue<<<(2 * N_) / 256, 256, 0, stream>>>(
      cloth_curr, cloth_next, fcurr, fnext, pmin, iter_num, out);
}